// Round 6
// baseline (239.490 us; speedup 1.0000x reference)
//
#include <hip/hip_runtime.h>
#include <stdint.h>

// logits = (mem^T @ x)/16 ; attn = softmax_M(logits) ; out = mem @ attn
// B=8, K=256, M=1024, N=4096.
// Split design: logits written by a dedicated GEMM1 kernel with 1KB-per-instruction
// row-chunk stores (m64 x n512 tiles); out produced by a fused GEMM1-recompute +
// softmax + GEMM2 kernel (writes only 34 MB). x pre-transposed to bf16 once.

typedef __attribute__((ext_vector_type(8))) __bf16 bf16x8;
typedef __attribute__((ext_vector_type(4))) float f32x4;
typedef __attribute__((ext_vector_type(4))) unsigned int u32x4;

#define BQ 8
#define KD 256
#define MD 1024
#define ND 4096
#define NT 64

__device__ __forceinline__ unsigned short bf16_rne(float f) {
    union { float f; uint32_t u; } c; c.f = f;
    uint32_t u = c.u;
    uint32_t r = (u + 0x7FFFu + ((u >> 16) & 1u)) >> 16;
    return (unsigned short)r;
}

// mem (f32 256x1024) -> mT bf16 [1024][256] (GEMM1 A-frags), mR bf16 [256][1024] (GEMM2 A-frags)
__global__ void prep_mem(const float* __restrict__ mem,
                         unsigned short* __restrict__ mT,
                         unsigned short* __restrict__ mR) {
    const int k = blockIdx.x;   // 0..255
    const int t = threadIdx.x;  // 0..255
    float4 v = reinterpret_cast<const float4*>(mem + (size_t)k * MD)[t];
    unsigned short h0 = bf16_rne(v.x), h1 = bf16_rne(v.y),
                   h2 = bf16_rne(v.z), h3 = bf16_rne(v.w);
    reinterpret_cast<uint2*>(mR + (size_t)k * MD)[t] =
        make_uint2((uint32_t)h0 | ((uint32_t)h1 << 16),
                   (uint32_t)h2 | ((uint32_t)h3 << 16));
    const int mm = t * 4;
    mT[(size_t)(mm + 0) * KD + k] = h0;
    mT[(size_t)(mm + 1) * KD + k] = h1;
    mT[(size_t)(mm + 2) * KD + k] = h2;
    mT[(size_t)(mm + 3) * KD + k] = h3;
}

// x f32 [b][k][n] -> xT bf16 [b][n][k] (contiguous 512B rows; block writes 32KB contiguous)
__global__ __launch_bounds__(1024, 4) void prep_xT(
    const float* __restrict__ x, unsigned short* __restrict__ xT)
{
    __shared__ __align__(16) char lds[32768];
    const int tid = threadIdx.x;
    const int b  = blockIdx.x >> 6;
    const int n0 = (blockIdx.x & 63) * 64;

    {
        const float* xb = x + (size_t)b * KD * ND + n0;
        const int k  = tid >> 2;        // 0..255
        const int nh = (tid & 3) * 16;  // 0,16,32,48
        const f32x4* src = reinterpret_cast<const f32x4*>(xb + (size_t)k * ND + nh);
        f32x4 v0 = __builtin_nontemporal_load(src + 0);
        f32x4 v1 = __builtin_nontemporal_load(src + 1);
        f32x4 v2 = __builtin_nontemporal_load(src + 2);
        f32x4 v3 = __builtin_nontemporal_load(src + 3);
        float vals[16] = {v0[0], v0[1], v0[2], v0[3], v1[0], v1[1], v1[2], v1[3],
                          v2[0], v2[1], v2[2], v2[3], v3[0], v3[1], v3[2], v3[3]};
        #pragma unroll
        for (int jj = 0; jj < 16; ++jj) {
            const int n = nh + jj;
            const int off = n * 512 + (((k >> 3) ^ (n & 7)) << 4) + (k & 7) * 2;
            *(unsigned short*)(lds + off) = bf16_rne(vals[jj]);
        }
    }
    __syncthreads();
    {
        const int n = tid >> 4, seg = tid & 15;
        u32x4 q0 = *(const u32x4*)(lds + n * 512 + (((2 * seg)     ^ (n & 7)) << 4));
        u32x4 q1 = *(const u32x4*)(lds + n * 512 + (((2 * seg + 1) ^ (n & 7)) << 4));
        u32x4* dst = (u32x4*)(xT + ((size_t)b * ND + n0 + n) * KD + seg * 16);
        dst[0] = q0;
        dst[1] = q1;
    }
}

// GEMM1 -> logits only. m-tile 64 x n-tile 512, 512 thr / 8 waves, no barriers.
// Operand frags direct from L2 (mT 512KB, xT slice 256KB per (b,nt), XCD-grouped).
// Stores: per-wave LDS transpose -> 1KB-contiguous dwordx4 nt stores (2KB per m-row per block).
__global__ __launch_bounds__(512, 2) void k_logits(
    const unsigned short* __restrict__ mT,
    const unsigned short* __restrict__ xT,
    float* __restrict__ logits)
{
    __shared__ __align__(16) float scr[8][4][256];   // 32 KB, wave-private slices

    const int tid = threadIdx.x;
    const int w   = tid >> 6;     // 0..7
    const int l   = tid & 63;
    const int l15 = l & 15;
    const int l4  = l >> 4;

    // XCD grouping: XCD g hosts 8 (b,nt) combos -> 2MB xT + 0.5MB mT resident per L2
    const int bid = blockIdx.x;         // 1024
    const int g   = bid & 7;
    const int j   = bid >> 3;           // 0..127
    const int c   = g * 8 + (j & 7);    // 0..63 (b,nt) combo
    const int mt  = j >> 3;             // 0..15
    const int b   = c >> 3;
    const int nt  = c & 7;

    const int m0w = mt * 64 + (w >> 1) * 16;
    const int n0w = nt * 512 + (w & 1) * 256;

    f32x4 acc[16];
    #pragma unroll
    for (int ct = 0; ct < 16; ++ct) acc[ct] = (f32x4){0.f, 0.f, 0.f, 0.f};

    #pragma unroll
    for (int ks = 0; ks < 8; ++ks) {
        const int kk = ks * 32 + l4 * 8;
        const bf16x8 a = *(const bf16x8*)(mT + (size_t)(m0w + l15) * KD + kk);
        #pragma unroll
        for (int ct = 0; ct < 16; ++ct) {
            const bf16x8 bf = *(const bf16x8*)(xT + ((size_t)b * ND + n0w + ct * 16 + l15) * KD + kk);
            acc[ct] = __builtin_amdgcn_mfma_f32_16x16x32_bf16(a, bf, acc[ct], 0, 0, 0);
        }
    }
    #pragma unroll
    for (int ct = 0; ct < 16; ++ct) acc[ct] = acc[ct] * 0.0625f;

    float* lgb = logits + (size_t)b * MD * ND;
    #pragma unroll
    for (int r = 0; r < 4; ++r) {
        #pragma unroll
        for (int ct = 0; ct < 16; ++ct) {
            const int nn = ct * 16 + l15;
            scr[w][l4][nn ^ (l4 << 3)] = acc[ct][r];
        }
        __asm__ volatile("s_waitcnt lgkmcnt(0)" ::: "memory");
        __builtin_amdgcn_sched_barrier(0);
        #pragma unroll
        for (int s = 0; s < 4; ++s) {
            const f32x4 v = *(const f32x4*)&scr[w][s][(4 * l) ^ (s << 3)];
            __builtin_nontemporal_store(v,
                (f32x4*)(lgb + (size_t)(m0w + s * 4 + r) * ND + n0w + 4 * l));
        }
        __asm__ volatile("s_waitcnt lgkmcnt(0)" ::: "memory");
        __builtin_amdgcn_sched_barrier(0);
    }
}

// Fused tail: GEMM1 recompute + softmax + GEMM2 -> out. (R5 structure minus logits phase.)
__global__ __launch_bounds__(1024, 4) void k_fused_tail(
    const unsigned short* __restrict__ xT,
    const unsigned short* __restrict__ mT,
    const unsigned short* __restrict__ mR,
    float* __restrict__ out)
{
    extern __shared__ char lds[];
    float* red_max = (float*)(lds);
    float* red_sum = (float*)(lds + 4096);

    const int tid = threadIdx.x;
    const int w   = tid >> 6;
    const int l   = tid & 63;
    const int l15 = l & 15;
    const int l4  = l >> 4;

    const int bid = blockIdx.x;         // 512
    const int g   = bid & 7;
    const int j   = bid >> 3;
    const int strip = g * 8 + (j & 7);
    const int b     = j >> 3;
    const int n0    = strip * NT;

    // ---- stage xT[b][n0:n0+64][:] -> LDS x^T tile (vector copy, re-swizzled) ----
    {
        const int n = tid >> 4, seg = tid & 15;
        const unsigned short* srow = xT + ((size_t)b * ND + n0 + n) * KD + seg * 16;
        u32x4 q0 = *(const u32x4*)(srow);
        u32x4 q1 = *(const u32x4*)(srow + 8);
        *(u32x4*)(lds + n * 512 + (((2 * seg)     ^ (n & 7)) << 4)) = q0;
        *(u32x4*)(lds + n * 512 + (((2 * seg + 1) ^ (n & 7)) << 4)) = q1;
    }
    __syncthreads();   // S1

    // ---- GEMM1: wave owns m-rows [w*64, w*64+64) x all 64 n ----
    f32x4 acc[4][4];
    #pragma unroll
    for (int rt = 0; rt < 4; ++rt)
        #pragma unroll
        for (int ct = 0; ct < 4; ++ct)
            acc[rt][ct] = (f32x4){0.f, 0.f, 0.f, 0.f};

    #pragma unroll
    for (int ks = 0; ks < 8; ++ks) {
        const int kk = ks * 32 + l4 * 8;
        bf16x8 bfr[4];
        #pragma unroll
        for (int ct = 0; ct < 4; ++ct) {
            const int n = ct * 16 + l15;
            const int off = n * 512 + (((kk >> 3) ^ (n & 7)) << 4);
            bfr[ct] = *(const bf16x8*)(lds + off);
        }
        #pragma unroll
        for (int rt = 0; rt < 4; ++rt) {
            const int row = w * 64 + rt * 16 + l15;
            const bf16x8 afr = *(const bf16x8*)(mT + (size_t)row * KD + kk);
            #pragma unroll
            for (int ct = 0; ct < 4; ++ct)
                acc[rt][ct] = __builtin_amdgcn_mfma_f32_16x16x32_bf16(afr, bfr[ct], acc[rt][ct], 0, 0, 0);
        }
    }

    // ---- scale 1/16 + per-column running max ----
    float lmax[4] = {-3e38f, -3e38f, -3e38f, -3e38f};
    #pragma unroll
    for (int rt = 0; rt < 4; ++rt) {
        #pragma unroll
        for (int ct = 0; ct < 4; ++ct) {
            f32x4 v = acc[rt][ct] * 0.0625f;
            acc[rt][ct] = v;
            lmax[ct] = fmaxf(lmax[ct], fmaxf(fmaxf(v[0], v[1]), fmaxf(v[2], v[3])));
        }
    }
    #pragma unroll
    for (int ct = 0; ct < 4; ++ct) {
        float m = lmax[ct];
        m = fmaxf(m, __shfl_xor(m, 16, 64));
        m = fmaxf(m, __shfl_xor(m, 32, 64));
        lmax[ct] = m;
    }
    __syncthreads();   // S2: x-tile reads done; red region (aliased) safe
    if (l < 16) {
        #pragma unroll
        for (int ct = 0; ct < 4; ++ct)
            red_max[(w * 4 + ct) * 16 + l] = lmax[ct];
    }
    __syncthreads();   // S3

    float cmax[4];
    #pragma unroll
    for (int ct = 0; ct < 4; ++ct) {
        float m = -3e38f;
        #pragma unroll
        for (int ww = 0; ww < 16; ++ww)
            m = fmaxf(m, red_max[(ww * 4 + ct) * 16 + l15]);
        cmax[ct] = m;
    }

    // ---- p = exp(logit - colmax), per-column sum ----
    float lsum[4] = {0.f, 0.f, 0.f, 0.f};
    #pragma unroll
    for (int rt = 0; rt < 4; ++rt) {
        #pragma unroll
        for (int ct = 0; ct < 4; ++ct) {
            f32x4 v = acc[rt][ct];
            v[0] = __expf(v[0] - cmax[ct]);
            v[1] = __expf(v[1] - cmax[ct]);
            v[2] = __expf(v[2] - cmax[ct]);
            v[3] = __expf(v[3] - cmax[ct]);
            lsum[ct] += (v[0] + v[1]) + (v[2] + v[3]);
            acc[rt][ct] = v;
        }
    }
    #pragma unroll
    for (int ct = 0; ct < 4; ++ct) {
        float s = lsum[ct];
        s += __shfl_xor(s, 16, 64);
        s += __shfl_xor(s, 32, 64);
        lsum[ct] = s;
    }
    if (l < 16) {
        #pragma unroll
        for (int ct = 0; ct < 4; ++ct)
            red_sum[(w * 4 + ct) * 16 + l] = lsum[ct];
    }
    __syncthreads();   // S4

    float rs[4];
    #pragma unroll
    for (int ct = 0; ct < 4; ++ct) {
        float s = 0.f;
        #pragma unroll
        for (int ww = 0; ww < 16; ++ww)
            s += red_sum[(ww * 4 + ct) * 16 + l15];
        rs[ct] = 1.0f / s;
    }

    // ---- attn (bf16) into LDS [n=64][m=1024], 16B-chunk XOR swizzle ----
    #pragma unroll
    for (int rt = 0; rt < 4; ++rt) {
        #pragma unroll
        for (int ct = 0; ct < 4; ++ct) {
            f32x4 v = acc[rt][ct];
            unsigned short h0 = bf16_rne(v[0] * rs[ct]);
            unsigned short h1 = bf16_rne(v[1] * rs[ct]);
            unsigned short h2 = bf16_rne(v[2] * rs[ct]);
            unsigned short h3 = bf16_rne(v[3] * rs[ct]);
            const int m0 = w * 64 + rt * 16 + l4 * 4;
            const int n  = ct * 16 + l15;
            const int off = 32768 + n * 2048 + (((m0 >> 3) ^ (n & 7)) << 4) + (m0 & 7) * 2;
            *(uint2*)(lds + off) = make_uint2((uint32_t)h0 | ((uint32_t)h1 << 16),
                                              (uint32_t)h2 | ((uint32_t)h3 << 16));
        }
    }
    __syncthreads();   // S5

    // ---- GEMM2: wave owns 16 out rows ----
    f32x4 acc2[4];
    #pragma unroll
    for (int ct = 0; ct < 4; ++ct)
        acc2[ct] = (f32x4){0.f, 0.f, 0.f, 0.f};

    const unsigned short* arow = mR + (size_t)(w * 16 + l15) * MD;
    #pragma unroll 4
    for (int ks = 0; ks < 32; ++ks) {
        const int mk = ks * 32 + l4 * 8;
        const bf16x8 a2 = *(const bf16x8*)(arow + mk);
        #pragma unroll
        for (int ct = 0; ct < 4; ++ct) {
            const int n = ct * 16 + l15;
            const int off = 32768 + n * 2048 + (((mk >> 3) ^ (n & 7)) << 4);
            const bf16x8 b2 = *(const bf16x8*)(lds + off);
            acc2[ct] = __builtin_amdgcn_mfma_f32_16x16x32_bf16(a2, b2, acc2[ct], 0, 0, 0);
        }
    }
    __syncthreads();   // S6

    // ---- out store via per-wave LDS transpose -> 256B contiguous dwordx4 ----
    {
        char* sw = lds + 32768 + w * 4608;
        float* ob = out + (size_t)b * KD * ND + n0;
        #pragma unroll
        for (int ct = 0; ct < 4; ++ct) {
            const int n = ct * 16 + l15;
            #pragma unroll
            for (int r = 0; r < 4; ++r) {
                const int rr = l4 * 4 + r;
                *(float*)(sw + rr * 272 + n * 4) = acc2[ct][r];
            }
        }
        __asm__ volatile("s_waitcnt lgkmcnt(0)" ::: "memory");
        __builtin_amdgcn_sched_barrier(0);
        #pragma unroll
        for (int p = 0; p < 4; ++p) {
            const int rr = p * 4 + l4;
            const f32x4 v = *(const f32x4*)(sw + rr * 272 + l15 * 16);
            __builtin_nontemporal_store(v,
                (f32x4*)(ob + (size_t)(w * 16 + rr) * ND + l15 * 4));
        }
    }
}

// ---------------- fallback (R5 fused kernel), used only if ws too small ----------------
__global__ __launch_bounds__(1024, 4) void fused_attn_mem(
    const float* __restrict__ x,
    const unsigned short* __restrict__ mT,
    const unsigned short* __restrict__ mR,
    float* __restrict__ out,
    float* __restrict__ logits)
{
    extern __shared__ char lds[];
    float* red_max = (float*)(lds);
    float* red_sum = (float*)(lds + 4096);
    const int tid = threadIdx.x;
    const int w = tid >> 6, l = tid & 63, l15 = l & 15, l4 = l >> 4;
    const int bid = blockIdx.x;
    const int g = bid & 7, j = bid >> 3;
    const int strip = g * 8 + (j & 7);
    const int b = j >> 3;
    const int n0 = strip * NT;
    {
        const float* xb = x + (size_t)b * KD * ND + n0;
        const int k = tid >> 2;
        const int nh = (tid & 3) * 16;
        const f32x4* src = reinterpret_cast<const f32x4*>(xb + (size_t)k * ND + nh);
        f32x4 v0 = src[0], v1 = src[1], v2 = src[2], v3 = src[3];
        float vals[16] = {v0[0], v0[1], v0[2], v0[3], v1[0], v1[1], v1[2], v1[3],
                          v2[0], v2[1], v2[2], v2[3], v3[0], v3[1], v3[2], v3[3]};
        #pragma unroll
        for (int jj = 0; jj < 16; ++jj) {
            const int n = nh + jj;
            const int off = n * 512 + (((k >> 3) ^ (n & 7)) << 4) + (k & 7) * 2;
            *(unsigned short*)(lds + off) = bf16_rne(vals[jj]);
        }
    }
    __syncthreads();
    f32x4 acc[4][4];
    #pragma unroll
    for (int rt = 0; rt < 4; ++rt)
        #pragma unroll
        for (int ct = 0; ct < 4; ++ct)
            acc[rt][ct] = (f32x4){0.f, 0.f, 0.f, 0.f};
    #pragma unroll
    for (int ks = 0; ks < 8; ++ks) {
        const int kk = ks * 32 + l4 * 8;
        bf16x8 bfr[4];
        #pragma unroll
        for (int ct = 0; ct < 4; ++ct) {
            const int n = ct * 16 + l15;
            bfr[ct] = *(const bf16x8*)(lds + n * 512 + (((kk >> 3) ^ (n & 7)) << 4));
        }
        #pragma unroll
        for (int rt = 0; rt < 4; ++rt) {
            const bf16x8 afr = *(const bf16x8*)(mT + (size_t)(w * 64 + rt * 16 + l15) * KD + kk);
            #pragma unroll
            for (int ct = 0; ct < 4; ++ct)
                acc[rt][ct] = __builtin_amdgcn_mfma_f32_16x16x32_bf16(afr, bfr[ct], acc[rt][ct], 0, 0, 0);
        }
    }
    float lmax[4] = {-3e38f, -3e38f, -3e38f, -3e38f};
    #pragma unroll
    for (int rt = 0; rt < 4; ++rt)
        #pragma unroll
        for (int ct = 0; ct < 4; ++ct) {
            f32x4 v = acc[rt][ct] * 0.0625f;
            acc[rt][ct] = v;
            lmax[ct] = fmaxf(lmax[ct], fmaxf(fmaxf(v[0], v[1]), fmaxf(v[2], v[3])));
        }
    {
        char* sw = lds + 34816 + w * 4608;
        float* lg = logits + (size_t)b * MD * ND + n0;
        #pragma unroll
        for (int rt = 0; rt < 4; ++rt) {
            #pragma unroll
            for (int ct = 0; ct < 4; ++ct) {
                const int n = ct * 16 + l15;
                #pragma unroll
                for (int r = 0; r < 4; ++r)
                    *(float*)(sw + (l4 * 4 + r) * 272 + n * 4) = acc[rt][ct][r];
            }
            __asm__ volatile("s_waitcnt lgkmcnt(0)" ::: "memory");
            __builtin_amdgcn_sched_barrier(0);
            #pragma unroll
            for (int p = 0; p < 4; ++p) {
                const int mloc = p * 4 + l4;
                const f32x4 v = *(const f32x4*)(sw + mloc * 272 + l15 * 16);
                *(f32x4*)(lg + (size_t)(w * 64 + rt * 16 + mloc) * ND + l15 * 4) = v;
            }
            __asm__ volatile("s_waitcnt lgkmcnt(0)" ::: "memory");
            __builtin_amdgcn_sched_barrier(0);
        }
    }
    #pragma unroll
    for (int ct = 0; ct < 4; ++ct) {
        float m = lmax[ct];
        m = fmaxf(m, __shfl_xor(m, 16, 64));
        m = fmaxf(m, __shfl_xor(m, 32, 64));
        lmax[ct] = m;
    }
    __syncthreads();
    if (l < 16)
        #pragma unroll
        for (int ct = 0; ct < 4; ++ct)
            red_max[(w * 4 + ct) * 16 + l] = lmax[ct];
    __syncthreads();
    float cmax[4];
    #pragma unroll
    for (int ct = 0; ct < 4; ++ct) {
        float m = -3e38f;
        #pragma unroll
        for (int ww = 0; ww < 16; ++ww)
            m = fmaxf(m, red_max[(ww * 4 + ct) * 16 + l15]);
        cmax[ct] = m;
    }
    float lsum[4] = {0.f, 0.f, 0.f, 0.f};
    #pragma unroll
    for (int rt = 0; rt < 4; ++rt)
        #pragma unroll
        for (int ct = 0; ct < 4; ++ct) {
            f32x4 v = acc[rt][ct];
            v[0] = __expf(v[0] - cmax[ct]); v[1] = __expf(v[1] - cmax[ct]);
            v[2] = __expf(v[2] - cmax[ct]); v[3] = __expf(v[3] - cmax[ct]);
            lsum[ct] += (v[0] + v[1]) + (v[2] + v[3]);
            acc[rt][ct] = v;
        }
    #pragma unroll
    for (int ct = 0; ct < 4; ++ct) {
        float s = lsum[ct];
        s += __shfl_xor(s, 16, 64);
        s += __shfl_xor(s, 32, 64);
        lsum[ct] = s;
    }
    if (l < 16)
        #pragma unroll
        for (int ct = 0; ct < 4; ++ct)
            red_sum[(w * 4 + ct) * 16 + l] = lsum[ct];
    __syncthreads();
    float rs[4];
    #pragma unroll
    for (int ct = 0; ct < 4; ++ct) {
        float s = 0.f;
        #pragma unroll
        for (int ww = 0; ww < 16; ++ww)
            s += red_sum[(ww * 4 + ct) * 16 + l15];
        rs[ct] = 1.0f / s;
    }
    __syncthreads();
    #pragma unroll
    for (int rt = 0; rt < 4; ++rt)
        #pragma unroll
        for (int ct = 0; ct < 4; ++ct) {
            f32x4 v = acc[rt][ct];
            unsigned short h0 = bf16_rne(v[0] * rs[ct]);
            unsigned short h1 = bf16_rne(v[1] * rs[ct]);
            unsigned short h2 = bf16_rne(v[2] * rs[ct]);
            unsigned short h3 = bf16_rne(v[3] * rs[ct]);
            const int m0 = w * 64 + rt * 16 + l4 * 4;
            const int n = ct * 16 + l15;
            const int off = 32768 + n * 2048 + (((m0 >> 3) ^ (n & 7)) << 4) + (m0 & 7) * 2;
            *(uint2*)(lds + off) = make_uint2((uint32_t)h0 | ((uint32_t)h1 << 16),
                                              (uint32_t)h2 | ((uint32_t)h3 << 16));
        }
    __syncthreads();
    f32x4 acc2[4];
    #pragma unroll
    for (int ct = 0; ct < 4; ++ct) acc2[ct] = (f32x4){0.f, 0.f, 0.f, 0.f};
    const unsigned short* arow = mR + (size_t)(w * 16 + l15) * MD;
    #pragma unroll 4
    for (int ks = 0; ks < 32; ++ks) {
        const int mk = ks * 32 + l4 * 8;
        const bf16x8 a2 = *(const bf16x8*)(arow + mk);
        #pragma unroll
        for (int ct = 0; ct < 4; ++ct) {
            const int n = ct * 16 + l15;
            const bf16x8 b2 = *(const bf16x8*)(lds + 32768 + n * 2048 + (((mk >> 3) ^ (n & 7)) << 4));
            acc2[ct] = __builtin_amdgcn_mfma_f32_16x16x32_bf16(a2, b2, acc2[ct], 0, 0, 0);
        }
    }
    __syncthreads();
    {
        char* sw = lds + 32768 + w * 4608;
        float* ob = out + (size_t)b * KD * ND + n0;
        #pragma unroll
        for (int ct = 0; ct < 4; ++ct) {
            const int n = ct * 16 + l15;
            #pragma unroll
            for (int r = 0; r < 4; ++r)
                *(float*)(sw + (l4 * 4 + r) * 272 + n * 4) = acc2[ct][r];
        }
        __asm__ volatile("s_waitcnt lgkmcnt(0)" ::: "memory");
        __builtin_amdgcn_sched_barrier(0);
        #pragma unroll
        for (int p = 0; p < 4; ++p) {
            const int rr = p * 4 + l4;
            const f32x4 v = *(const f32x4*)(sw + rr * 272 + l15 * 16);
            *(f32x4*)(ob + (size_t)(w * 16 + rr) * ND + l15 * 4) = v;
        }
    }
}

extern "C" void kernel_launch(void* const* d_in, const int* in_sizes, int n_in,
                              void* d_out, int out_size, void* d_ws, size_t ws_size,
                              hipStream_t stream) {
    (void)in_sizes; (void)n_in; (void)out_size;
    const float* x   = (const float*)d_in[0];
    // d_in[1] (mask) is a forward no-op
    const float* mem = (const float*)d_in[2];

    float* out    = (float*)d_out;
    float* logits = (float*)d_out + (size_t)BQ * KD * ND;

    unsigned short* mT = (unsigned short*)d_ws;                 // [1024][256] bf16
    unsigned short* mR = mT + (size_t)MD * KD;                  // [256][1024] bf16
    unsigned short* xT = (unsigned short*)((char*)d_ws + 1048576);  // [8][4096][256] bf16

    const size_t need = 1048576 + (size_t)BQ * ND * KD * 2;     // ~17.8 MB

    prep_mem<<<dim3(256), dim3(256), 0, stream>>>(mem, mT, mR);

    if (ws_size >= need) {
        static int attr_set = 0;
        if (!attr_set) {
            (void)hipFuncSetAttribute(reinterpret_cast<const void*>(&k_fused_tail),
                                      hipFuncAttributeMaxDynamicSharedMemorySize, 163840);
            attr_set = 1;
        }
        prep_xT<<<dim3(512), dim3(1024), 0, stream>>>(x, xT);
        k_logits<<<dim3(1024), dim3(512), 0, stream>>>(mT, xT, logits);
        k_fused_tail<<<dim3(512), dim3(1024), 163840, stream>>>(xT, mT, mR, out);
    } else {
        static int attr_set2 = 0;
        if (!attr_set2) {
            (void)hipFuncSetAttribute(reinterpret_cast<const void*>(&fused_attn_mem),
                                      hipFuncAttributeMaxDynamicSharedMemorySize, 163840);
            attr_set2 = 1;
        }
        fused_attn_mem<<<dim3(512), dim3(1024), 163840, stream>>>(x, mT, mR, out, logits);
    }
}

// Round 7
// 146.561 us; speedup vs baseline: 1.6341x; 1.6341x over previous
//
#include <hip/hip_runtime.h>
#include <stdint.h>

// logits = (mem^T @ x)/16 ; attn = softmax_M(logits) ; out = mem @ attn
// B=8, K=256, M=1024, N=4096. Single fused kernel.
// Key idea this round: NEVER drain vmcnt mid-kernel (raw s_barrier + lgkmcnt-only
// fences) so nt stores stay in flight under all later compute; 512-thr blocks with
// 80KB LDS + <=128 unified regs -> 2 blocks/CU for cross-block compute/drain overlap.

typedef __attribute__((ext_vector_type(8))) __bf16 bf16x8;
typedef __attribute__((ext_vector_type(4))) float f32x4;

#define BQ 8
#define KD 256
#define MD 1024
#define ND 4096
#define NT 32

// barrier that does NOT drain vmcnt (global stores stay in flight)
#define RAW_BAR() do {                                           \
    __asm__ volatile("s_waitcnt lgkmcnt(0)" ::: "memory");       \
    __builtin_amdgcn_sched_barrier(0);                           \
    __builtin_amdgcn_s_barrier();                                \
    __builtin_amdgcn_sched_barrier(0);                           \
} while (0)

__device__ __forceinline__ unsigned short bf16_rne(float f) {
    union { float f; uint32_t u; } c; c.f = f;
    uint32_t u = c.u;
    uint32_t r = (u + 0x7FFFu + ((u >> 16) & 1u)) >> 16;
    return (unsigned short)r;
}

// mem (f32 256x1024) -> mT bf16 [1024][256] (GEMM1 A-frags), mR bf16 [256][1024] (GEMM2 A-frags)
__global__ void prep_mem(const float* __restrict__ mem,
                         unsigned short* __restrict__ mT,
                         unsigned short* __restrict__ mR) {
    const int k = blockIdx.x;   // 0..255
    const int t = threadIdx.x;  // 0..255
    float4 v = reinterpret_cast<const float4*>(mem + (size_t)k * MD)[t];
    unsigned short h0 = bf16_rne(v.x), h1 = bf16_rne(v.y),
                   h2 = bf16_rne(v.z), h3 = bf16_rne(v.w);
    reinterpret_cast<uint2*>(mR + (size_t)k * MD)[t] =
        make_uint2((uint32_t)h0 | ((uint32_t)h1 << 16),
                   (uint32_t)h2 | ((uint32_t)h3 << 16));
    const int mm = t * 4;
    mT[(size_t)(mm + 0) * KD + k] = h0;
    mT[(size_t)(mm + 1) * KD + k] = h1;
    mT[(size_t)(mm + 2) * KD + k] = h2;
    mT[(size_t)(mm + 3) * KD + k] = h3;
}

// One workgroup = (batch b, 32-column strip). 8 waves, 512 threads, 2 blocks/CU.
// Dynamic LDS 80 KiB:
//   [0,16K):      x^T tile [n=32][k=256] bf16, swizzled (dead after GEMM1)
//   [16K,17K):    red_max   [17K,18K): red_sum        (live S2..S4, alias attn)
//   [18K,34K):    per-wave transpose scratch 8x2KB    (logits phase + out phase)
//   [16K,80K):    attn tile [n=32][m=1024] bf16       (after S4b)
__global__ __launch_bounds__(512, 4) void fused_attn_mem(
    const float* __restrict__ x,
    const unsigned short* __restrict__ mT,
    const unsigned short* __restrict__ mR,
    float* __restrict__ out,
    float* __restrict__ logits)
{
    extern __shared__ char lds[];
    float* red_max = (float*)(lds + 16384);
    float* red_sum = (float*)(lds + 17408);

    const int tid = threadIdx.x;
    const int w   = tid >> 6;     // wave 0..7
    const int l   = tid & 63;
    const int l15 = l & 15;
    const int l4  = l >> 4;       // 0..3

    // XCD grouping: XCD g owns strips [g*16, g*16+16) for all batches
    const int bid = blockIdx.x;          // 1024 blocks
    const int g   = bid & 7;
    const int j   = bid >> 3;            // 0..127
    const int strip = g * 16 + (j & 15); // 0..127
    const int b     = j >> 4;            // 0..7
    const int n0    = strip * NT;

    // ---- stage x[b][:][n0:n0+32] -> LDS x^T [n][k], bf16, swizzled ----
    {
        const float* xb = x + (size_t)b * KD * ND + n0;
        const int k  = tid >> 1;        // 0..255
        const int nh = (tid & 1) * 16;  // 0 or 16
        const f32x4* src = reinterpret_cast<const f32x4*>(xb + (size_t)k * ND + nh);
        f32x4 v0 = __builtin_nontemporal_load(src + 0);
        f32x4 v1 = __builtin_nontemporal_load(src + 1);
        f32x4 v2 = __builtin_nontemporal_load(src + 2);
        f32x4 v3 = __builtin_nontemporal_load(src + 3);
        float vals[16] = {v0[0], v0[1], v0[2], v0[3], v1[0], v1[1], v1[2], v1[3],
                          v2[0], v2[1], v2[2], v2[3], v3[0], v3[1], v3[2], v3[3]};
        #pragma unroll
        for (int jj = 0; jj < 16; ++jj) {
            const int n = nh + jj;
            const int off = n * 512 + (((k >> 3) ^ (n & 7)) << 4) + (k & 7) * 2;
            *(unsigned short*)(lds + off) = bf16_rne(vals[jj]);
        }
    }
    RAW_BAR();   // S1

    // ---- GEMM1: S[m][n]; wave owns m-rows [w*128, w*128+128) x 32 n ----
    f32x4 acc[8][2];
    #pragma unroll
    for (int rt = 0; rt < 8; ++rt)
        #pragma unroll
        for (int ct = 0; ct < 2; ++ct)
            acc[rt][ct] = (f32x4){0.f, 0.f, 0.f, 0.f};

    #pragma unroll
    for (int ks = 0; ks < 8; ++ks) {
        const int kk = ks * 32 + l4 * 8;
        bf16x8 bfr[2];
        #pragma unroll
        for (int ct = 0; ct < 2; ++ct) {
            const int n = ct * 16 + l15;
            const int off = n * 512 + (((kk >> 3) ^ (n & 7)) << 4);
            bfr[ct] = *(const bf16x8*)(lds + off);
        }
        #pragma unroll
        for (int rt = 0; rt < 8; ++rt) {
            const int row = w * 128 + rt * 16 + l15;
            const bf16x8 afr = *(const bf16x8*)(mT + (size_t)row * KD + kk);
            acc[rt][0] = __builtin_amdgcn_mfma_f32_16x16x32_bf16(afr, bfr[0], acc[rt][0], 0, 0, 0);
            acc[rt][1] = __builtin_amdgcn_mfma_f32_16x16x32_bf16(afr, bfr[1], acc[rt][1], 0, 0, 0);
        }
    }

    // ---- scale 1/16 + per-column running max ----
    float lmax[2] = {-3e38f, -3e38f};
    #pragma unroll
    for (int rt = 0; rt < 8; ++rt) {
        #pragma unroll
        for (int ct = 0; ct < 2; ++ct) {
            f32x4 v = acc[rt][ct] * 0.0625f;
            acc[rt][ct] = v;
            lmax[ct] = fmaxf(lmax[ct], fmaxf(fmaxf(v[0], v[1]), fmaxf(v[2], v[3])));
        }
    }

    // ---- logits: per-wave LDS transpose -> 128B-row nt dwordx4 stores (stay in flight) ----
    {
        char* sw = lds + 18432 + w * 2048;   // [16 m][32 n] f32, XOR'd 16B chunks
        float* lg = logits + (size_t)b * MD * ND + n0;
        #pragma unroll
        for (int rt = 0; rt < 8; ++rt) {
            #pragma unroll
            for (int ct = 0; ct < 2; ++ct) {
                const int n = ct * 16 + l15;
                #pragma unroll
                for (int r = 0; r < 4; ++r) {
                    const int mloc = l4 * 4 + r;
                    const int off = mloc * 128 + (((n >> 2) ^ (mloc & 7)) << 4) + ((n & 3) << 2);
                    *(float*)(sw + off) = acc[rt][ct][r];
                }
            }
            __asm__ volatile("s_waitcnt lgkmcnt(0)" ::: "memory");
            __builtin_amdgcn_sched_barrier(0);
            #pragma unroll
            for (int half = 0; half < 2; ++half) {
                const int mloc = (l >> 3) + half * 8;
                const int q = l & 7;
                const f32x4 v = *(const f32x4*)(sw + mloc * 128 + ((q ^ (mloc & 7)) << 4));
                __builtin_nontemporal_store(v,
                    (f32x4*)(lg + (size_t)(w * 128 + rt * 16 + mloc) * ND + q * 4));
            }
            __asm__ volatile("s_waitcnt lgkmcnt(0)" ::: "memory");
            __builtin_amdgcn_sched_barrier(0);
        }
    }

    // ---- cross-wave column max ----
    #pragma unroll
    for (int ct = 0; ct < 2; ++ct) {
        float m = lmax[ct];
        m = fmaxf(m, __shfl_xor(m, 16, 64));
        m = fmaxf(m, __shfl_xor(m, 32, 64));
        lmax[ct] = m;
    }
    RAW_BAR();   // S2: x-tile + scratch reads done everywhere; red region safe
    if (l < 16) {
        red_max[(w * 2 + 0) * 16 + l] = lmax[0];
        red_max[(w * 2 + 1) * 16 + l] = lmax[1];
    }
    RAW_BAR();   // S3

    float cmax[2];
    #pragma unroll
    for (int ct = 0; ct < 2; ++ct) {
        float m = -3e38f;
        #pragma unroll
        for (int ww = 0; ww < 8; ++ww)
            m = fmaxf(m, red_max[(ww * 2 + ct) * 16 + l15]);
        cmax[ct] = m;
    }

    // ---- p = exp(logit - colmax), per-column sum ----
    float lsum[2] = {0.f, 0.f};
    #pragma unroll
    for (int rt = 0; rt < 8; ++rt) {
        #pragma unroll
        for (int ct = 0; ct < 2; ++ct) {
            f32x4 v = acc[rt][ct];
            v[0] = __expf(v[0] - cmax[ct]);
            v[1] = __expf(v[1] - cmax[ct]);
            v[2] = __expf(v[2] - cmax[ct]);
            v[3] = __expf(v[3] - cmax[ct]);
            lsum[ct] += (v[0] + v[1]) + (v[2] + v[3]);
            acc[rt][ct] = v;
        }
    }
    #pragma unroll
    for (int ct = 0; ct < 2; ++ct) {
        float s = lsum[ct];
        s += __shfl_xor(s, 16, 64);
        s += __shfl_xor(s, 32, 64);
        lsum[ct] = s;
    }
    if (l < 16) {
        red_sum[(w * 2 + 0) * 16 + l] = lsum[0];
        red_sum[(w * 2 + 1) * 16 + l] = lsum[1];
    }
    RAW_BAR();   // S4

    float rs[2];
    #pragma unroll
    for (int ct = 0; ct < 2; ++ct) {
        float s = 0.f;
        #pragma unroll
        for (int ww = 0; ww < 8; ++ww)
            s += red_sum[(ww * 2 + ct) * 16 + l15];
        rs[ct] = 1.0f / s;
    }
    RAW_BAR();   // S4b: red reads done; attn tile may overwrite [16K,80K)

    // ---- attn (bf16) into LDS [n=32][m=1024] at +16K, 16B-chunk XOR swizzle ----
    #pragma unroll
    for (int rt = 0; rt < 8; ++rt) {
        #pragma unroll
        for (int ct = 0; ct < 2; ++ct) {
            f32x4 v = acc[rt][ct];
            unsigned short h0 = bf16_rne(v[0] * rs[ct]);
            unsigned short h1 = bf16_rne(v[1] * rs[ct]);
            unsigned short h2 = bf16_rne(v[2] * rs[ct]);
            unsigned short h3 = bf16_rne(v[3] * rs[ct]);
            const int m0 = w * 128 + rt * 16 + l4 * 4;
            const int n  = ct * 16 + l15;
            const int off = 16384 + n * 2048 + (((m0 >> 3) ^ (n & 7)) << 4) + (m0 & 7) * 2;
            *(uint2*)(lds + off) = make_uint2((uint32_t)h0 | ((uint32_t)h1 << 16),
                                              (uint32_t)h2 | ((uint32_t)h3 << 16));
        }
    }
    RAW_BAR();   // S5

    // ---- GEMM2: out[r][n] = sum_m mR[r][m]*attn[m][n]; wave owns rows [w*32, w*32+32) ----
    f32x4 acc2[2][2];
    #pragma unroll
    for (int rtile = 0; rtile < 2; ++rtile)
        #pragma unroll
        for (int ct = 0; ct < 2; ++ct)
            acc2[rtile][ct] = (f32x4){0.f, 0.f, 0.f, 0.f};

    #pragma unroll 4
    for (int ks = 0; ks < 32; ++ks) {
        const int mk = ks * 32 + l4 * 8;
        bf16x8 b2[2];
        #pragma unroll
        for (int ct = 0; ct < 2; ++ct) {
            const int n = ct * 16 + l15;
            const int off = 16384 + n * 2048 + (((mk >> 3) ^ (n & 7)) << 4);
            b2[ct] = *(const bf16x8*)(lds + off);
        }
        #pragma unroll
        for (int rtile = 0; rtile < 2; ++rtile) {
            const bf16x8 a2 = *(const bf16x8*)(mR + (size_t)(w * 32 + rtile * 16 + l15) * MD + mk);
            acc2[rtile][0] = __builtin_amdgcn_mfma_f32_16x16x32_bf16(a2, b2[0], acc2[rtile][0], 0, 0, 0);
            acc2[rtile][1] = __builtin_amdgcn_mfma_f32_16x16x32_bf16(a2, b2[1], acc2[rtile][1], 0, 0, 0);
        }
    }
    RAW_BAR();   // S6: attn reads done; scratch region reusable

    // ---- out store via per-wave LDS transpose -> 128B-row nt dwordx4 ----
    {
        char* sw = lds + 18432 + w * 2048;
        float* ob = out + (size_t)b * KD * ND + n0;
        #pragma unroll
        for (int rtile = 0; rtile < 2; ++rtile) {
            #pragma unroll
            for (int ct = 0; ct < 2; ++ct) {
                const int n = ct * 16 + l15;
                #pragma unroll
                for (int r = 0; r < 4; ++r) {
                    const int rr = l4 * 4 + r;
                    const int off = rr * 128 + (((n >> 2) ^ (rr & 7)) << 4) + ((n & 3) << 2);
                    *(float*)(sw + off) = acc2[rtile][ct][r];
                }
            }
            __asm__ volatile("s_waitcnt lgkmcnt(0)" ::: "memory");
            __builtin_amdgcn_sched_barrier(0);
            #pragma unroll
            for (int half = 0; half < 2; ++half) {
                const int rr = (l >> 3) + half * 8;
                const int q = l & 7;
                const f32x4 v = *(const f32x4*)(sw + rr * 128 + ((q ^ (rr & 7)) << 4));
                __builtin_nontemporal_store(v,
                    (f32x4*)(ob + (size_t)(w * 32 + rtile * 16 + rr) * ND + q * 4));
            }
            __asm__ volatile("s_waitcnt lgkmcnt(0)" ::: "memory");
            __builtin_amdgcn_sched_barrier(0);
        }
    }
}

extern "C" void kernel_launch(void* const* d_in, const int* in_sizes, int n_in,
                              void* d_out, int out_size, void* d_ws, size_t ws_size,
                              hipStream_t stream) {
    (void)in_sizes; (void)n_in; (void)out_size; (void)ws_size;
    const float* x   = (const float*)d_in[0];
    // d_in[1] (mask) is a forward no-op
    const float* mem = (const float*)d_in[2];

    float* out    = (float*)d_out;
    float* logits = (float*)d_out + (size_t)BQ * KD * ND;

    unsigned short* mT = (unsigned short*)d_ws;        // [1024][256] bf16
    unsigned short* mR = mT + (size_t)MD * KD;         // [256][1024] bf16

    static int lds_attr_set = 0;   // idempotent host-side attribute, capture-safe
    if (!lds_attr_set) {
        (void)hipFuncSetAttribute(reinterpret_cast<const void*>(&fused_attn_mem),
                                  hipFuncAttributeMaxDynamicSharedMemorySize, 81920);
        lds_attr_set = 1;
    }

    prep_mem<<<dim3(256), dim3(256), 0, stream>>>(mem, mT, mR);
    fused_attn_mem<<<dim3(BQ * (ND / NT)), dim3(512), 81920, stream>>>(x, mT, mR, out, logits);
}

// Round 8
// 140.682 us; speedup vs baseline: 1.7023x; 1.0418x over previous
//
#include <hip/hip_runtime.h>
#include <stdint.h>

// logits = (mem^T @ x)/16 ; attn = softmax_M(logits) ; out = mem @ attn
// B=8, K=256, M=1024, N=4096.
// Persistent fused kernel: 256 blocks (1/CU), each handles ONE 64-col strip for
// batches b and b+4 back-to-back. Strip-2 x-prefetch issues first (oldest vmcnt),
// strip-2 staging/GEMM1 overlaps strip-1 store drain; no round-boundary bubble.

typedef __attribute__((ext_vector_type(8))) __bf16 bf16x8;
typedef __attribute__((ext_vector_type(4))) float f32x4;

#define BQ 8
#define KD 256
#define MD 1024
#define ND 4096
#define NT 64

#define RAW_BAR() do {                                           \
    __asm__ volatile("s_waitcnt lgkmcnt(0)" ::: "memory");       \
    __builtin_amdgcn_sched_barrier(0);                           \
    __builtin_amdgcn_s_barrier();                                \
    __builtin_amdgcn_sched_barrier(0);                           \
} while (0)

__device__ __forceinline__ unsigned short bf16_rne(float f) {
    union { float f; uint32_t u; } c; c.f = f;
    uint32_t u = c.u;
    uint32_t r = (u + 0x7FFFu + ((u >> 16) & 1u)) >> 16;
    return (unsigned short)r;
}

// mem (f32 256x1024) -> mT bf16 [1024][256], mR bf16 [256][1024]
__global__ void prep_mem(const float* __restrict__ mem,
                         unsigned short* __restrict__ mT,
                         unsigned short* __restrict__ mR) {
    const int k = blockIdx.x;
    const int t = threadIdx.x;
    float4 v = reinterpret_cast<const float4*>(mem + (size_t)k * MD)[t];
    unsigned short h0 = bf16_rne(v.x), h1 = bf16_rne(v.y),
                   h2 = bf16_rne(v.z), h3 = bf16_rne(v.w);
    reinterpret_cast<uint2*>(mR + (size_t)k * MD)[t] =
        make_uint2((uint32_t)h0 | ((uint32_t)h1 << 16),
                   (uint32_t)h2 | ((uint32_t)h3 << 16));
    const int mm = t * 4;
    mT[(size_t)(mm + 0) * KD + k] = h0;
    mT[(size_t)(mm + 1) * KD + k] = h1;
    mT[(size_t)(mm + 2) * KD + k] = h2;
    mT[(size_t)(mm + 3) * KD + k] = h3;
}

// stage 16 f32 (row k, cols nh..nh+15) into swizzled bf16 x^T tile at lds[0,32K)
__device__ __forceinline__ void stage_tile(char* lds, const f32x4* pre, int tid) {
    const int k  = tid >> 2;
    const int nh = (tid & 3) * 16;
    float vals[16] = {pre[0][0], pre[0][1], pre[0][2], pre[0][3],
                      pre[1][0], pre[1][1], pre[1][2], pre[1][3],
                      pre[2][0], pre[2][1], pre[2][2], pre[2][3],
                      pre[3][0], pre[3][1], pre[3][2], pre[3][3]};
    #pragma unroll
    for (int jj = 0; jj < 16; ++jj) {
        const int n = nh + jj;
        const int off = n * 512 + (((k >> 3) ^ (n & 7)) << 4) + (k & 7) * 2;
        *(unsigned short*)(lds + off) = bf16_rne(vals[jj]);
    }
}

__device__ __forceinline__ void load_tile(const float* __restrict__ xb,
                                          f32x4* pre, int tid) {
    const int k  = tid >> 2;
    const int nh = (tid & 3) * 16;
    const f32x4* src = reinterpret_cast<const f32x4*>(xb + (size_t)k * ND + nh);
    pre[0] = __builtin_nontemporal_load(src + 0);
    pre[1] = __builtin_nontemporal_load(src + 1);
    pre[2] = __builtin_nontemporal_load(src + 2);
    pre[3] = __builtin_nontemporal_load(src + 3);
}

// One strip's full pipeline. IT==0 additionally prefetches+stages the next strip's
// x tile: loads issue at body start (oldest in vmcnt queue -> retire before any
// store drain), ds_write lands after S5 when [0,32K) is dead.
template <int IT>
__device__ __forceinline__ void strip_body(
    char* __restrict__ lds,
    const unsigned short* __restrict__ mT,
    const unsigned short* __restrict__ mR,
    float* __restrict__ lg, float* __restrict__ ob,
    const float* __restrict__ x_next,
    int tid, int w, int l, int l15, int l4)
{
    float* red_max = (float*)(lds);
    float* red_sum = (float*)(lds + 4096);

    f32x4 pre[4];
    if (IT == 0) {
        load_tile(x_next, pre, tid);   // issue earliest; data needed only after S5
    }

    // ---- GEMM1: wave owns m-rows [w*64, w*64+64) x all 64 n ----
    f32x4 acc[4][4];
    #pragma unroll
    for (int rt = 0; rt < 4; ++rt)
        #pragma unroll
        for (int ct = 0; ct < 4; ++ct)
            acc[rt][ct] = (f32x4){0.f, 0.f, 0.f, 0.f};

    #pragma unroll
    for (int ks = 0; ks < 8; ++ks) {
        const int kk = ks * 32 + l4 * 8;
        bf16x8 bfr[4];
        #pragma unroll
        for (int ct = 0; ct < 4; ++ct) {
            const int n = ct * 16 + l15;
            const int off = n * 512 + (((kk >> 3) ^ (n & 7)) << 4);
            bfr[ct] = *(const bf16x8*)(lds + off);
        }
        #pragma unroll
        for (int rt = 0; rt < 4; ++rt) {
            const int row = w * 64 + rt * 16 + l15;
            const bf16x8 afr = *(const bf16x8*)(mT + (size_t)row * KD + kk);
            #pragma unroll
            for (int ct = 0; ct < 4; ++ct)
                acc[rt][ct] = __builtin_amdgcn_mfma_f32_16x16x32_bf16(afr, bfr[ct], acc[rt][ct], 0, 0, 0);
        }
    }

    // ---- scale 1/16 + per-column running max ----
    float lmax[4] = {-3e38f, -3e38f, -3e38f, -3e38f};
    #pragma unroll
    for (int rt = 0; rt < 4; ++rt) {
        #pragma unroll
        for (int ct = 0; ct < 4; ++ct) {
            f32x4 v = acc[rt][ct] * 0.0625f;
            acc[rt][ct] = v;
            lmax[ct] = fmaxf(lmax[ct], fmaxf(fmaxf(v[0], v[1]), fmaxf(v[2], v[3])));
        }
    }

    // ---- logits: per-wave LDS transpose -> 256B-contiguous nt dwordx4 ----
    {
        char* sw = lds + 32768 + w * 4608;   // [16 m][68 dword] f32
        #pragma unroll
        for (int rt = 0; rt < 4; ++rt) {
            #pragma unroll
            for (int ct = 0; ct < 4; ++ct) {
                const int n = ct * 16 + l15;
                #pragma unroll
                for (int r = 0; r < 4; ++r) {
                    const int mloc = l4 * 4 + r;
                    *(float*)(sw + mloc * 272 + n * 4) = acc[rt][ct][r];
                }
            }
            __asm__ volatile("s_waitcnt lgkmcnt(0)" ::: "memory");
            __builtin_amdgcn_sched_barrier(0);
            #pragma unroll
            for (int p = 0; p < 4; ++p) {
                const int mloc = p * 4 + l4;
                const f32x4 v = *(const f32x4*)(sw + mloc * 272 + l15 * 16);
                __builtin_nontemporal_store(v,
                    (f32x4*)(lg + (size_t)(w * 64 + rt * 16 + mloc) * ND + l15 * 4));
            }
            __asm__ volatile("s_waitcnt lgkmcnt(0)" ::: "memory");
            __builtin_amdgcn_sched_barrier(0);
        }
    }

    // ---- cross-wave column max ----
    #pragma unroll
    for (int ct = 0; ct < 4; ++ct) {
        float m = lmax[ct];
        m = fmaxf(m, __shfl_xor(m, 16, 64));
        m = fmaxf(m, __shfl_xor(m, 32, 64));
        lmax[ct] = m;
    }
    RAW_BAR();   // S2: x-tile + scratch reads done; red region safe
    if (l < 16) {
        #pragma unroll
        for (int ct = 0; ct < 4; ++ct)
            red_max[(w * 4 + ct) * 16 + l] = lmax[ct];
    }
    RAW_BAR();   // S3

    float cmax[4];
    #pragma unroll
    for (int ct = 0; ct < 4; ++ct) {
        float m = -3e38f;
        #pragma unroll
        for (int ww = 0; ww < 16; ++ww)
            m = fmaxf(m, red_max[(ww * 4 + ct) * 16 + l15]);
        cmax[ct] = m;
    }

    // ---- p = exp(logit - colmax), per-column sum ----
    float lsum[4] = {0.f, 0.f, 0.f, 0.f};
    #pragma unroll
    for (int rt = 0; rt < 4; ++rt) {
        #pragma unroll
        for (int ct = 0; ct < 4; ++ct) {
            f32x4 v = acc[rt][ct];
            v[0] = __expf(v[0] - cmax[ct]);
            v[1] = __expf(v[1] - cmax[ct]);
            v[2] = __expf(v[2] - cmax[ct]);
            v[3] = __expf(v[3] - cmax[ct]);
            lsum[ct] += (v[0] + v[1]) + (v[2] + v[3]);
            acc[rt][ct] = v;
        }
    }
    #pragma unroll
    for (int ct = 0; ct < 4; ++ct) {
        float s = lsum[ct];
        s += __shfl_xor(s, 16, 64);
        s += __shfl_xor(s, 32, 64);
        lsum[ct] = s;
    }
    if (l < 16) {
        #pragma unroll
        for (int ct = 0; ct < 4; ++ct)
            red_sum[(w * 4 + ct) * 16 + l] = lsum[ct];
    }
    RAW_BAR();   // S4

    float rs[4];
    #pragma unroll
    for (int ct = 0; ct < 4; ++ct) {
        float s = 0.f;
        #pragma unroll
        for (int ww = 0; ww < 16; ++ww)
            s += red_sum[(ww * 4 + ct) * 16 + l15];
        rs[ct] = 1.0f / s;
    }
    RAW_BAR();   // S4b: red reads done

    // ---- attn (bf16) into LDS [n=64][m=1024] at +32K ----
    #pragma unroll
    for (int rt = 0; rt < 4; ++rt) {
        #pragma unroll
        for (int ct = 0; ct < 4; ++ct) {
            f32x4 v = acc[rt][ct];
            unsigned short h0 = bf16_rne(v[0] * rs[ct]);
            unsigned short h1 = bf16_rne(v[1] * rs[ct]);
            unsigned short h2 = bf16_rne(v[2] * rs[ct]);
            unsigned short h3 = bf16_rne(v[3] * rs[ct]);
            const int m0 = w * 64 + rt * 16 + l4 * 4;
            const int n  = ct * 16 + l15;
            const int off = 32768 + n * 2048 + (((m0 >> 3) ^ (n & 7)) << 4) + (m0 & 7) * 2;
            *(uint2*)(lds + off) = make_uint2((uint32_t)h0 | ((uint32_t)h1 << 16),
                                              (uint32_t)h2 | ((uint32_t)h3 << 16));
        }
    }
    RAW_BAR();   // S5

    // ---- stage next strip's tile into dead [0,32K) (pre regs long retired) ----
    if (IT == 0) {
        stage_tile(lds, pre, tid);
        // no barrier here: visibility ensured by later fences + S1' in caller
    }

    // ---- GEMM2: wave owns 16 out rows ----
    f32x4 acc2[4];
    #pragma unroll
    for (int ct = 0; ct < 4; ++ct)
        acc2[ct] = (f32x4){0.f, 0.f, 0.f, 0.f};

    const unsigned short* arow = mR + (size_t)(w * 16 + l15) * MD;
    #pragma unroll 4
    for (int ks = 0; ks < 32; ++ks) {
        const int mk = ks * 32 + l4 * 8;
        const bf16x8 a2 = *(const bf16x8*)(arow + mk);
        #pragma unroll
        for (int ct = 0; ct < 4; ++ct) {
            const int n = ct * 16 + l15;
            const int off = 32768 + n * 2048 + (((mk >> 3) ^ (n & 7)) << 4);
            const bf16x8 b2 = *(const bf16x8*)(lds + off);
            acc2[ct] = __builtin_amdgcn_mfma_f32_16x16x32_bf16(a2, b2, acc2[ct], 0, 0, 0);
        }
    }
    RAW_BAR();   // S6: attn reads done; scratch region reusable

    // ---- out store via per-wave LDS transpose -> 256B nt dwordx4 ----
    {
        char* sw = lds + 32768 + w * 4608;
        #pragma unroll
        for (int ct = 0; ct < 4; ++ct) {
            const int n = ct * 16 + l15;
            #pragma unroll
            for (int r = 0; r < 4; ++r) {
                const int rr = l4 * 4 + r;
                *(float*)(sw + rr * 272 + n * 4) = acc2[ct][r];
            }
        }
        __asm__ volatile("s_waitcnt lgkmcnt(0)" ::: "memory");
        __builtin_amdgcn_sched_barrier(0);
        #pragma unroll
        for (int p = 0; p < 4; ++p) {
            const int rr = p * 4 + l4;
            const f32x4 v = *(const f32x4*)(sw + rr * 272 + l15 * 16);
            __builtin_nontemporal_store(v,
                (f32x4*)(ob + (size_t)(w * 16 + rr) * ND + l15 * 4));
        }
        __asm__ volatile("s_waitcnt lgkmcnt(0)" ::: "memory");
        __builtin_amdgcn_sched_barrier(0);
    }
}

// 256 persistent blocks, 1024 thr (16 waves), 160 KiB dynamic LDS, 1 block/CU.
__global__ __launch_bounds__(1024, 4) void fused_attn_mem(
    const float* __restrict__ x,
    const unsigned short* __restrict__ mT,
    const unsigned short* __restrict__ mR,
    float* __restrict__ out,
    float* __restrict__ logits)
{
    extern __shared__ char lds[];

    const int tid = threadIdx.x;
    const int w   = tid >> 6;
    const int l   = tid & 63;
    const int l15 = l & 15;
    const int l4  = l >> 4;

    const int q  = blockIdx.x;        // 0..255
    const int g  = q & 7;             // XCD
    const int j  = q >> 3;            // 0..31
    const int strip = g * 8 + (j & 7);
    const int b0    = j >> 3;         // 0..3
    const int b1    = b0 + 4;
    const int n0    = strip * NT;

    const float* x0 = x + (size_t)b0 * KD * ND + n0;
    const float* x1 = x + (size_t)b1 * KD * ND + n0;
    float* lg0 = logits + (size_t)b0 * MD * ND + n0;
    float* lg1 = logits + (size_t)b1 * MD * ND + n0;
    float* ob0 = out + (size_t)b0 * KD * ND + n0;
    float* ob1 = out + (size_t)b1 * KD * ND + n0;

    // prologue: stage strip-0 tile
    {
        f32x4 p0[4];
        load_tile(x0, p0, tid);
        stage_tile(lds, p0, tid);
    }
    RAW_BAR();   // S1

    strip_body<0>(lds, mT, mR, lg0, ob0, x1, tid, w, l, l15, l4);
    RAW_BAR();   // S1': strip-1 tile (staged during body 0) visible to all waves
    strip_body<1>(lds, mT, mR, lg1, ob1, nullptr, tid, w, l, l15, l4);
}

extern "C" void kernel_launch(void* const* d_in, const int* in_sizes, int n_in,
                              void* d_out, int out_size, void* d_ws, size_t ws_size,
                              hipStream_t stream) {
    (void)in_sizes; (void)n_in; (void)out_size; (void)ws_size;
    const float* x   = (const float*)d_in[0];
    // d_in[1] (mask) is a forward no-op
    const float* mem = (const float*)d_in[2];

    float* out    = (float*)d_out;
    float* logits = (float*)d_out + (size_t)BQ * KD * ND;

    unsigned short* mT = (unsigned short*)d_ws;        // [1024][256] bf16
    unsigned short* mR = mT + (size_t)MD * KD;         // [256][1024] bf16

    static int lds_attr_set = 0;
    if (!lds_attr_set) {
        (void)hipFuncSetAttribute(reinterpret_cast<const void*>(&fused_attn_mem),
                                  hipFuncAttributeMaxDynamicSharedMemorySize, 163840);
        lds_attr_set = 1;
    }

    prep_mem<<<dim3(256), dim3(256), 0, stream>>>(mem, mT, mR);
    fused_attn_mem<<<dim3(256), dim3(1024), 163840, stream>>>(x, mT, mR, out, logits);
}

// Round 9
// 133.757 us; speedup vs baseline: 1.7905x; 1.0518x over previous
//
#include <hip/hip_runtime.h>
#include <stdint.h>

// logits = (mem^T @ x)/16 ; attn = softmax_M(logits) ; out = mem @ attn
// B=8, K=256, M=1024, N=4096.
// Persistent fused kernel (256 blocks, 1/CU), 2 strip-bodies per block.
// R9: plain cached stores (nt-store amplification removed), softmax max-reduce
// hoisted BEFORE the logits store burst so exp/attn/GEMM2 drain stores in-shadow.

typedef __attribute__((ext_vector_type(8))) __bf16 bf16x8;
typedef __attribute__((ext_vector_type(4))) float f32x4;

#define BQ 8
#define KD 256
#define MD 1024
#define ND 4096
#define NT 64

#define RAW_BAR() do {                                           \
    __asm__ volatile("s_waitcnt lgkmcnt(0)" ::: "memory");       \
    __builtin_amdgcn_sched_barrier(0);                           \
    __builtin_amdgcn_s_barrier();                                \
    __builtin_amdgcn_sched_barrier(0);                           \
} while (0)

__device__ __forceinline__ unsigned short bf16_rne(float f) {
    union { float f; uint32_t u; } c; c.f = f;
    uint32_t u = c.u;
    uint32_t r = (u + 0x7FFFu + ((u >> 16) & 1u)) >> 16;
    return (unsigned short)r;
}

// mem (f32 256x1024) -> mT bf16 [1024][256], mR bf16 [256][1024]
__global__ void prep_mem(const float* __restrict__ mem,
                         unsigned short* __restrict__ mT,
                         unsigned short* __restrict__ mR) {
    const int k = blockIdx.x;
    const int t = threadIdx.x;
    float4 v = reinterpret_cast<const float4*>(mem + (size_t)k * MD)[t];
    unsigned short h0 = bf16_rne(v.x), h1 = bf16_rne(v.y),
                   h2 = bf16_rne(v.z), h3 = bf16_rne(v.w);
    reinterpret_cast<uint2*>(mR + (size_t)k * MD)[t] =
        make_uint2((uint32_t)h0 | ((uint32_t)h1 << 16),
                   (uint32_t)h2 | ((uint32_t)h3 << 16));
    const int mm = t * 4;
    mT[(size_t)(mm + 0) * KD + k] = h0;
    mT[(size_t)(mm + 1) * KD + k] = h1;
    mT[(size_t)(mm + 2) * KD + k] = h2;
    mT[(size_t)(mm + 3) * KD + k] = h3;
}

// stage 16 f32 (row k, cols nh..nh+15) into swizzled bf16 x^T tile at lds[0,32K)
__device__ __forceinline__ void stage_tile(char* lds, const f32x4* pre, int tid) {
    const int k  = tid >> 2;
    const int nh = (tid & 3) * 16;
    float vals[16] = {pre[0][0], pre[0][1], pre[0][2], pre[0][3],
                      pre[1][0], pre[1][1], pre[1][2], pre[1][3],
                      pre[2][0], pre[2][1], pre[2][2], pre[2][3],
                      pre[3][0], pre[3][1], pre[3][2], pre[3][3]};
    #pragma unroll
    for (int jj = 0; jj < 16; ++jj) {
        const int n = nh + jj;
        const int off = n * 512 + (((k >> 3) ^ (n & 7)) << 4) + (k & 7) * 2;
        *(unsigned short*)(lds + off) = bf16_rne(vals[jj]);
    }
}

__device__ __forceinline__ void load_tile(const float* __restrict__ xb,
                                          f32x4* pre, int tid) {
    const int k  = tid >> 2;
    const int nh = (tid & 3) * 16;
    const f32x4* src = reinterpret_cast<const f32x4*>(xb + (size_t)k * ND + nh);
    pre[0] = __builtin_nontemporal_load(src + 0);
    pre[1] = __builtin_nontemporal_load(src + 1);
    pre[2] = __builtin_nontemporal_load(src + 2);
    pre[3] = __builtin_nontemporal_load(src + 3);
}

// One strip's pipeline. IT==0 prefetches + stages the next strip's x tile.
template <int IT>
__device__ __forceinline__ void strip_body(
    char* __restrict__ lds,
    const unsigned short* __restrict__ mT,
    const unsigned short* __restrict__ mR,
    float* __restrict__ lg, float* __restrict__ ob,
    const float* __restrict__ x_next,
    int tid, int w, int l, int l15, int l4)
{
    float* red_max = (float*)(lds);
    float* red_sum = (float*)(lds + 4096);

    f32x4 pre[4];
    if (IT == 0) {
        load_tile(x_next, pre, tid);   // oldest in vmcnt queue; used after S5
    }

    // ---- GEMM1: wave owns m-rows [w*64, w*64+64) x all 64 n ----
    f32x4 acc[4][4];
    #pragma unroll
    for (int rt = 0; rt < 4; ++rt)
        #pragma unroll
        for (int ct = 0; ct < 4; ++ct)
            acc[rt][ct] = (f32x4){0.f, 0.f, 0.f, 0.f};

    #pragma unroll
    for (int ks = 0; ks < 8; ++ks) {
        const int kk = ks * 32 + l4 * 8;
        bf16x8 bfr[4];
        #pragma unroll
        for (int ct = 0; ct < 4; ++ct) {
            const int n = ct * 16 + l15;
            const int off = n * 512 + (((kk >> 3) ^ (n & 7)) << 4);
            bfr[ct] = *(const bf16x8*)(lds + off);
        }
        #pragma unroll
        for (int rt = 0; rt < 4; ++rt) {
            const int row = w * 64 + rt * 16 + l15;
            const bf16x8 afr = *(const bf16x8*)(mT + (size_t)row * KD + kk);
            #pragma unroll
            for (int ct = 0; ct < 4; ++ct)
                acc[rt][ct] = __builtin_amdgcn_mfma_f32_16x16x32_bf16(afr, bfr[ct], acc[rt][ct], 0, 0, 0);
        }
    }

    // ---- scale 1/16 + per-column max + cross-wave reduce (BEFORE store burst) ----
    float lmax[4] = {-3e38f, -3e38f, -3e38f, -3e38f};
    #pragma unroll
    for (int rt = 0; rt < 4; ++rt) {
        #pragma unroll
        for (int ct = 0; ct < 4; ++ct) {
            f32x4 v = acc[rt][ct] * 0.0625f;
            acc[rt][ct] = v;
            lmax[ct] = fmaxf(lmax[ct], fmaxf(fmaxf(v[0], v[1]), fmaxf(v[2], v[3])));
        }
    }
    #pragma unroll
    for (int ct = 0; ct < 4; ++ct) {
        float m = lmax[ct];
        m = fmaxf(m, __shfl_xor(m, 16, 64));
        m = fmaxf(m, __shfl_xor(m, 32, 64));
        lmax[ct] = m;
    }
    RAW_BAR();   // S2: x-tile reads done everywhere; red region safe to write
    if (l < 16) {
        #pragma unroll
        for (int ct = 0; ct < 4; ++ct)
            red_max[(w * 4 + ct) * 16 + l] = lmax[ct];
    }
    RAW_BAR();   // S3

    float cmax[4];
    #pragma unroll
    for (int ct = 0; ct < 4; ++ct) {
        float m = -3e38f;
        #pragma unroll
        for (int ww = 0; ww < 16; ++ww)
            m = fmaxf(m, red_max[(ww * 4 + ct) * 16 + l15]);
        cmax[ct] = m;
    }

    // ---- logits: per-wave LDS transpose -> 256B-contiguous cached dwordx4 ----
    // No barrier after this until S4: exp/sum compute drains stores in-shadow.
    {
        char* sw = lds + 32768 + w * 4608;   // [16 m][68 dword] f32
        #pragma unroll
        for (int rt = 0; rt < 4; ++rt) {
            #pragma unroll
            for (int ct = 0; ct < 4; ++ct) {
                const int n = ct * 16 + l15;
                #pragma unroll
                for (int r = 0; r < 4; ++r) {
                    const int mloc = l4 * 4 + r;
                    *(float*)(sw + mloc * 272 + n * 4) = acc[rt][ct][r];
                }
            }
            __asm__ volatile("s_waitcnt lgkmcnt(0)" ::: "memory");
            __builtin_amdgcn_sched_barrier(0);
            #pragma unroll
            for (int p = 0; p < 4; ++p) {
                const int mloc = p * 4 + l4;
                const f32x4 v = *(const f32x4*)(sw + mloc * 272 + l15 * 16);
                *(f32x4*)(lg + (size_t)(w * 64 + rt * 16 + mloc) * ND + l15 * 4) = v;
            }
            __asm__ volatile("s_waitcnt lgkmcnt(0)" ::: "memory");
            __builtin_amdgcn_sched_barrier(0);
        }
    }

    // ---- p = exp(logit - colmax), per-column sum (overlaps store drain) ----
    float lsum[4] = {0.f, 0.f, 0.f, 0.f};
    #pragma unroll
    for (int rt = 0; rt < 4; ++rt) {
        #pragma unroll
        for (int ct = 0; ct < 4; ++ct) {
            f32x4 v = acc[rt][ct];
            v[0] = __expf(v[0] - cmax[ct]);
            v[1] = __expf(v[1] - cmax[ct]);
            v[2] = __expf(v[2] - cmax[ct]);
            v[3] = __expf(v[3] - cmax[ct]);
            lsum[ct] += (v[0] + v[1]) + (v[2] + v[3]);
            acc[rt][ct] = v;
        }
    }
    #pragma unroll
    for (int ct = 0; ct < 4; ++ct) {
        float s = lsum[ct];
        s += __shfl_xor(s, 16, 64);
        s += __shfl_xor(s, 32, 64);
        lsum[ct] = s;
    }
    if (l < 16) {
        #pragma unroll
        for (int ct = 0; ct < 4; ++ct)
            red_sum[(w * 4 + ct) * 16 + l] = lsum[ct];
    }
    RAW_BAR();   // S4

    float rs[4];
    #pragma unroll
    for (int ct = 0; ct < 4; ++ct) {
        float s = 0.f;
        #pragma unroll
        for (int ww = 0; ww < 16; ++ww)
            s += red_sum[(ww * 4 + ct) * 16 + l15];
        rs[ct] = 1.0f / s;
    }
    RAW_BAR();   // S4b: red reads done

    // ---- attn (bf16) into LDS [n=64][m=1024] at +32K ----
    #pragma unroll
    for (int rt = 0; rt < 4; ++rt) {
        #pragma unroll
        for (int ct = 0; ct < 4; ++ct) {
            f32x4 v = acc[rt][ct];
            unsigned short h0 = bf16_rne(v[0] * rs[ct]);
            unsigned short h1 = bf16_rne(v[1] * rs[ct]);
            unsigned short h2 = bf16_rne(v[2] * rs[ct]);
            unsigned short h3 = bf16_rne(v[3] * rs[ct]);
            const int m0 = w * 64 + rt * 16 + l4 * 4;
            const int n  = ct * 16 + l15;
            const int off = 32768 + n * 2048 + (((m0 >> 3) ^ (n & 7)) << 4) + (m0 & 7) * 2;
            *(uint2*)(lds + off) = make_uint2((uint32_t)h0 | ((uint32_t)h1 << 16),
                                              (uint32_t)h2 | ((uint32_t)h3 << 16));
        }
    }
    RAW_BAR();   // S5

    // ---- stage next strip's tile into dead [0,32K) ----
    if (IT == 0) {
        stage_tile(lds, pre, tid);
    }

    // ---- GEMM2: wave owns 16 out rows ----
    f32x4 acc2[4];
    #pragma unroll
    for (int ct = 0; ct < 4; ++ct)
        acc2[ct] = (f32x4){0.f, 0.f, 0.f, 0.f};

    const unsigned short* arow = mR + (size_t)(w * 16 + l15) * MD;
    #pragma unroll 4
    for (int ks = 0; ks < 32; ++ks) {
        const int mk = ks * 32 + l4 * 8;
        const bf16x8 a2 = *(const bf16x8*)(arow + mk);
        #pragma unroll
        for (int ct = 0; ct < 4; ++ct) {
            const int n = ct * 16 + l15;
            const int off = 32768 + n * 2048 + (((mk >> 3) ^ (n & 7)) << 4);
            const bf16x8 b2 = *(const bf16x8*)(lds + off);
            acc2[ct] = __builtin_amdgcn_mfma_f32_16x16x32_bf16(a2, b2, acc2[ct], 0, 0, 0);
        }
    }
    RAW_BAR();   // S6: attn reads done; scratch region reusable

    // ---- out store via per-wave LDS transpose -> 256B cached dwordx4 ----
    {
        char* sw = lds + 32768 + w * 4608;
        #pragma unroll
        for (int ct = 0; ct < 4; ++ct) {
            const int n = ct * 16 + l15;
            #pragma unroll
            for (int r = 0; r < 4; ++r) {
                const int rr = l4 * 4 + r;
                *(float*)(sw + rr * 272 + n * 4) = acc2[ct][r];
            }
        }
        __asm__ volatile("s_waitcnt lgkmcnt(0)" ::: "memory");
        __builtin_amdgcn_sched_barrier(0);
        #pragma unroll
        for (int p = 0; p < 4; ++p) {
            const int rr = p * 4 + l4;
            const f32x4 v = *(const f32x4*)(sw + rr * 272 + l15 * 16);
            *(f32x4*)(ob + (size_t)(w * 16 + rr) * ND + l15 * 4) = v;
        }
        __asm__ volatile("s_waitcnt lgkmcnt(0)" ::: "memory");
        __builtin_amdgcn_sched_barrier(0);
    }
}

// 256 persistent blocks, 1024 thr (16 waves), 160 KiB dynamic LDS, 1 block/CU.
__global__ __launch_bounds__(1024, 4) void fused_attn_mem(
    const float* __restrict__ x,
    const unsigned short* __restrict__ mT,
    const unsigned short* __restrict__ mR,
    float* __restrict__ out,
    float* __restrict__ logits)
{
    extern __shared__ char lds[];

    const int tid = threadIdx.x;
    const int w   = tid >> 6;
    const int l   = tid & 63;
    const int l15 = l & 15;
    const int l4  = l >> 4;

    const int q  = blockIdx.x;        // 0..255
    const int g  = q & 7;             // XCD
    const int j  = q >> 3;            // 0..31
    const int strip = g * 8 + (j & 7);
    const int b0    = j >> 3;         // 0..3
    const int b1    = b0 + 4;
    const int n0    = strip * NT;

    const float* x0 = x + (size_t)b0 * KD * ND + n0;
    const float* x1 = x + (size_t)b1 * KD * ND + n0;
    float* lg0 = logits + (size_t)b0 * MD * ND + n0;
    float* lg1 = logits + (size_t)b1 * MD * ND + n0;
    float* ob0 = out + (size_t)b0 * KD * ND + n0;
    float* ob1 = out + (size_t)b1 * KD * ND + n0;

    {
        f32x4 p0[4];
        load_tile(x0, p0, tid);
        stage_tile(lds, p0, tid);
    }
    RAW_BAR();   // S1

    strip_body<0>(lds, mT, mR, lg0, ob0, x1, tid, w, l, l15, l4);
    RAW_BAR();   // S1': strip-1 tile visible
    strip_body<1>(lds, mT, mR, lg1, ob1, nullptr, tid, w, l, l15, l4);
}

extern "C" void kernel_launch(void* const* d_in, const int* in_sizes, int n_in,
                              void* d_out, int out_size, void* d_ws, size_t ws_size,
                              hipStream_t stream) {
    (void)in_sizes; (void)n_in; (void)out_size; (void)ws_size;
    const float* x   = (const float*)d_in[0];
    // d_in[1] (mask) is a forward no-op
    const float* mem = (const float*)d_in[2];

    float* out    = (float*)d_out;
    float* logits = (float*)d_out + (size_t)BQ * KD * ND;

    unsigned short* mT = (unsigned short*)d_ws;        // [1024][256] bf16
    unsigned short* mR = mT + (size_t)MD * KD;         // [256][1024] bf16

    static int lds_attr_set = 0;
    if (!lds_attr_set) {
        (void)hipFuncSetAttribute(reinterpret_cast<const void*>(&fused_attn_mem),
                                  hipFuncAttributeMaxDynamicSharedMemorySize, 163840);
        lds_attr_set = 1;
    }

    prep_mem<<<dim3(256), dim3(256), 0, stream>>>(mem, mT, mR);
    fused_attn_mem<<<dim3(256), dim3(1024), 163840, stream>>>(x, mT, mR, out, logits);
}